// Round 1
// baseline (39732.916 us; speedup 1.0000x reference)
//
#include <hip/hip_runtime.h>

// ---------------------------------------------------------------------------
// Graves handwriting synthesis: 3x peephole-LSTM(400) + soft window attention
// + MDN head.  B=32, T=400.  Persistent-kernel design, 2 grid barriers/step.
//
// Block 0           : attention (att matmul, kappa/phi, window w) each step
// Blocks 1..200     : each owns 2 units (8 gate cols) of ALL three layers.
// Software pipeline per step t:
//   P(t): att(t)->w(t) | finish z3(t-1) (+h2 part) -> h3(t-1)
//         | partials z2(t) (x,h1,h2 parts), z1(t+1) (x,h1 parts)   [barrier]
//   Q(t): z2 += w part -> h2(t); z1 += w part -> h1(t+1);
//         z3(t) partials (x,w,h3 parts)                             [barrier]
// Epilogue: MDN GEMM + softmax/exp/tanh/sigmoid transforms (parallel).
// ---------------------------------------------------------------------------

#define NBLK   201
#define NTHR   512
#define TSTEPS 400
#define BATCH  32
#define UNITSN 400
#define NCHARS 73
#define UC     50
#define KTOT   2228   // 476 (z1) + 876 (z2) + 876 (z3)

// ws float offsets (state region [0, 40768) is zeroed by hipMemsetAsync)
#define BAR_CNT_OFF 0
#define BAR_EP_OFF  16
#define H1_OFF      32
#define H2_OFF      (H1_OFF + 12800)
#define H3_OFF      (H2_OFF + 12800)
#define WW_OFF      (H3_OFF + 12800)            // window buf 32*73 = 2336
#define HS_OFF      40768                       // h3 history [T][B][400]
#define WBLK_OFF    (HS_OFF + 12800 * 400)      // reordered weights [200][8][KTOT]
#define STATE_BYTES (40768 * 4)
// total ws need: (WBLK_OFF + 200*8*KTOT)*4  ~= 34.9 MB

__device__ __forceinline__ float sigf(float x)   { return 1.0f / (1.0f + __expf(-x)); }
__device__ __forceinline__ float tanhf_(float x) { return 1.0f - 2.0f / (1.0f + __expf(2.0f * x)); }

__device__ __forceinline__ float dot400(const float* __restrict__ w,
                                        const float* __restrict__ x, int kh) {
  const float4* wv = (const float4*)(w + kh * 200);
  const float4* xv = (const float4*)(x + kh * 200);
  float s0 = 0.f, s1 = 0.f, s2 = 0.f, s3 = 0.f;
#pragma unroll 5
  for (int i = 0; i < 50; ++i) {
    float4 a = wv[i], bb = xv[i];
    s0 = fmaf(a.x, bb.x, s0); s1 = fmaf(a.y, bb.y, s1);
    s2 = fmaf(a.z, bb.z, s2); s3 = fmaf(a.w, bb.w, s3);
  }
  return (s0 + s1) + (s2 + s3);
}

__device__ __forceinline__ float dot73(const float* __restrict__ w,
                                       const float* __restrict__ x, int kh) {
  int st = kh * 37;
  int en = st + (kh ? 36 : 37);
  float s = 0.f;
  for (int k = st; k < en; ++k) s = fmaf(w[k], x[k], s);
  return s;
}

extern "C" __global__ void __launch_bounds__(NTHR, 1)
hand_kernel(const float* __restrict__ xs, const int* __restrict__ chars,
            const int* __restrict__ lens,
            const float* __restrict__ Wx0, const float* __restrict__ Wh0,
            const float* __restrict__ b0, const float* __restrict__ p0,
            const float* __restrict__ Wx1, const float* __restrict__ Wh1,
            const float* __restrict__ b1, const float* __restrict__ p1,
            const float* __restrict__ Wx2, const float* __restrict__ Wh2,
            const float* __restrict__ b2, const float* __restrict__ p2,
            const float* __restrict__ Watt, const float* __restrict__ batt,
            const float* __restrict__ Wmdn, const float* __restrict__ bmdn,
            float* __restrict__ dout, float* __restrict__ ws) {
  const int blk = blockIdx.x;
  const int tid = threadIdx.x;

  __shared__ float zpart[NTHR];
  __shared__ float zbuf[256];
  __shared__ float biasL[3][8];
  __shared__ float peepL[3][3][2];
  __shared__ float cstate[3][64];     // [layer][ul*32 + b]
  __shared__ int   bar_target;
  __shared__ float attacc[960];
  __shared__ float alphaL[320], betaL[320], kappaL[320];
  __shared__ float wlds[BATCH * NCHARS];

  int* bar_cnt = (int*)(ws + BAR_CNT_OFF);
  int* bar_ep  = (int*)(ws + BAR_EP_OFF);
  float* h1buf = ws + H1_OFF;
  float* h2buf = ws + H2_OFF;
  float* h3buf = ws + H3_OFF;
  float* wbuf  = ws + WW_OFF;
  float* hs    = ws + HS_OFF;

  const int out = tid & 255;
  const int b   = out >> 3;    // batch 0..31
  const int c   = out & 7;     // col: (c>>2)=unit_local, (c&3)=gate (i,f,g,o)
  const int kh  = tid >> 8;    // k-half 0/1
  const int u0  = 2 * (blk - 1);

  float* Wmy = ws + WBLK_OFF + (size_t)(blk > 0 ? blk - 1 : 0) * (8 * KTOT);

  if (tid == 0) bar_target = 0;
  if (tid < 192) cstate[tid / 64][tid % 64] = 0.f;
  if (tid < 320) kappaL[tid] = 0.f;

  if (blk > 0) {
    // gather this block's weight columns into contiguous col-major layout
    for (int idx = tid; idx < 8 * KTOT; idx += NTHR) {
      int cc = idx / KTOT, k = idx - cc * KTOT;
      int gcol = (cc & 3) * UNITSN + u0 + (cc >> 2);
      float v;
      if (k < 476)        v = (k < 76) ? Wx0[k * 1600 + gcol] : Wh0[(k - 76) * 1600 + gcol];
      else if (k < 1352) { int kk = k - 476;  v = (kk < 476) ? Wx1[kk * 1600 + gcol] : Wh1[(kk - 476) * 1600 + gcol]; }
      else               { int kk = k - 1352; v = (kk < 476) ? Wx2[kk * 1600 + gcol] : Wh2[(kk - 476) * 1600 + gcol]; }
      Wmy[cc * KTOT + k] = v;
    }
    if (tid < 24) {
      int l = tid >> 3, cc = tid & 7;
      const float* bs = (l == 0) ? b0 : (l == 1) ? b1 : b2;
      biasL[l][cc] = bs[(cc & 3) * UNITSN + u0 + (cc >> 2)];
    }
    if (tid < 18) {
      int l = tid / 6, r = (tid % 6) >> 1, ul = tid & 1;
      const float* ps = (l == 0) ? p0 : (l == 1) ? p1 : p2;
      peepL[l][r][ul] = ps[r * UNITSN + u0 + ul];
    }
  }
  __syncthreads();

  auto gridbar = [&]() {
    __syncthreads();
    if (tid == 0) {
      __threadfence();  // release: make our global writes visible device-wide
      int tgt = ++bar_target;
      int prev = __hip_atomic_fetch_add(bar_cnt, 1, __ATOMIC_ACQ_REL, __HIP_MEMORY_SCOPE_AGENT);
      if (prev == NBLK - 1) {
        __hip_atomic_store(bar_cnt, 0, __ATOMIC_RELAXED, __HIP_MEMORY_SCOPE_AGENT);
        __hip_atomic_store(bar_ep, tgt, __ATOMIC_RELEASE, __HIP_MEMORY_SCOPE_AGENT);
      } else {
        while (__hip_atomic_load(bar_ep, __ATOMIC_RELAXED, __HIP_MEMORY_SCOPE_AGENT) < tgt)
          __builtin_amdgcn_s_sleep(1);
      }
      __threadfence();  // acquire: invalidate caches so we see others' writes
    }
    __syncthreads();
  };

  auto finalize = [&](int layer, float acc, float* hdst, float* hdst2) {
    zpart[tid] = acc;
    __syncthreads();
    if (tid < 256) zbuf[tid] = zpart[tid] + zpart[tid + 256] + biasL[layer][tid & 7];
    __syncthreads();
    if (tid < 256 && (tid & 3) == 0) {
      int bb = tid >> 3, ul = (tid & 7) >> 2;
      float zi = zbuf[tid], zf = zbuf[tid + 1], zg = zbuf[tid + 2], zo = zbuf[tid + 3];
      float cold = cstate[layer][ul * 32 + bb];
      float ig = sigf(zi + peepL[layer][0][ul] * cold);
      float fg = sigf(zf + peepL[layer][1][ul] * cold);
      float cn = fg * cold + ig * tanhf_(zg);
      float og = sigf(zo + peepL[layer][2][ul] * cn);
      float h  = og * tanhf_(cn);
      cstate[layer][ul * 32 + bb] = cn;
      int u = u0 + ul;
      hdst[bb * UNITSN + u] = h;
      if (hdst2) hdst2[bb * UNITSN + u] = h;
    }
    __syncthreads();
  };

  auto attention = [&]() {
    for (int i = tid; i < 960; i += NTHR) attacc[i] = 0.f;
    __syncthreads();
    {
      int ab = tid & 31, ks = tid >> 5;  // 32 batches x 16 k-slices of 25
      float accs[30];
#pragma unroll
      for (int j = 0; j < 30; ++j) accs[j] = 0.f;
      const float* h1b = h1buf + ab * UNITSN + ks * 25;
      const float* wr  = Watt + (ks * 25) * 30;
      for (int kk = 0; kk < 25; ++kk) {
        float hv = h1b[kk];
#pragma unroll
        for (int j = 0; j < 30; ++j) accs[j] = fmaf(hv, wr[kk * 30 + j], accs[j]);
      }
#pragma unroll
      for (int j = 0; j < 30; ++j) atomicAdd(&attacc[ab * 30 + j], accs[j]);
    }
    __syncthreads();
    if (tid < 320) {
      int bb = tid / 10, j = tid - bb * 10;
      float ah   = attacc[bb * 30 + j]      + batt[j];
      float bh   = attacc[bb * 30 + 10 + j] + batt[10 + j];
      float khat = attacc[bb * 30 + 20 + j] + batt[20 + j];
      float kap = kappaL[tid] + __expf(khat);
      kappaL[tid] = kap;
      alphaL[tid] = __expf(ah);
      betaL[tid]  = __expf(bh);
    }
    for (int i = tid; i < BATCH * NCHARS; i += NTHR) wlds[i] = 0.f;
    __syncthreads();
    for (int idx = tid; idx < BATCH * UC; idx += NTHR) {
      int bb = idx / UC, u = idx - bb * UC;
      if (u < lens[bb]) {
        float ph = 0.f;
#pragma unroll
        for (int j = 0; j < 10; ++j) {
          float d = kappaL[bb * 10 + j] - (float)u;
          ph = fmaf(alphaL[bb * 10 + j], __expf(-betaL[bb * 10 + j] * d * d), ph);
        }
        atomicAdd(&wlds[bb * NCHARS + chars[bb * UC + u]], ph);
      }
    }
    __syncthreads();
    for (int i = tid; i < BATCH * NCHARS; i += NTHR) wbuf[i] = wlds[i];
  };

  const float* h1row = h1buf + b * UNITSN;
  const float* h2row = h2buf + b * UNITSN;
  const float* h3row = h3buf + b * UNITSN;
  const float* wrow  = wbuf + b * NCHARS;
  const float* Wc0   = Wmy + c * KTOT;

  // ---- prologue: h1(0) = gates(x(0) @ Wx0[x-rows] + b0), all state zero ----
  if (blk > 0) {
    float acc = 0.f;
    if (kh == 0) {
      const float* xr = xs + (b * TSTEPS + 0) * 3;
      acc = Wc0[0] * xr[0] + Wc0[1] * xr[1] + Wc0[2] * xr[2];
    }
    finalize(0, acc, h1buf, nullptr);
  }
  gridbar();

  float acc_z1 = 0.f, acc_z2 = 0.f, acc_z3 = 0.f;
  for (int t = 0; t < TSTEPS; ++t) {
    // ------------------------------ P(t) ------------------------------
    if (blk == 0) {
      attention();
    } else {
      if (t > 0) {
        float a3 = acc_z3 + dot400(Wc0 + 1428, h2row, kh);  // + h2(t-1) part
        finalize(2, a3, h3buf, hs + (size_t)(t - 1) * 12800);
      }
      float a2 = dot400(Wc0 + 552, h1row, kh) + dot400(Wc0 + 952, h2row, kh);
      float a1 = 0.f;
      if (t < TSTEPS - 1) a1 = dot400(Wc0 + 76, h1row, kh);
      if (kh == 0) {
        const float* xr = xs + (b * TSTEPS + t) * 3;
        a2 += Wc0[476] * xr[0] + Wc0[477] * xr[1] + Wc0[478] * xr[2];
        if (t < TSTEPS - 1) {
          const float* x1 = xs + (b * TSTEPS + t + 1) * 3;
          a1 += Wc0[0] * x1[0] + Wc0[1] * x1[1] + Wc0[2] * x1[2];
        }
      }
      acc_z2 = a2;
      acc_z1 = a1;
    }
    gridbar();
    // ------------------------------ Q(t) ------------------------------
    if (blk > 0) {
      acc_z2 += dot73(Wc0 + 479, wrow, kh);
      finalize(1, acc_z2, h2buf, nullptr);
      if (t < TSTEPS - 1) {
        acc_z1 += dot73(Wc0 + 3, wrow, kh);
        finalize(0, acc_z1, h1buf, nullptr);
      }
      float a3 = dot400(Wc0 + 1828, h3row, kh) + dot73(Wc0 + 1355, wrow, kh);
      if (kh == 0) {
        const float* xr = xs + (b * TSTEPS + t) * 3;
        a3 += Wc0[1352] * xr[0] + Wc0[1353] * xr[1] + Wc0[1354] * xr[2];
      }
      acc_z3 = a3;
    }
    gridbar();
  }
  // ---- epilogue step: finish z3(T-1) -> h3(T-1) ----
  if (blk > 0) {
    float a3 = acc_z3 + dot400(Wc0 + 1428, h2row, kh);
    finalize(2, a3, h3buf, hs + (size_t)(TSTEPS - 1) * 12800);
  }
  gridbar();

  // ---- MDN head + output transforms (parallel over 12800 (b,t) rows) ----
  {
    int j = tid & 127, ks = tid >> 7;
    for (int i0 = 0; i0 < 64; i0 += 4) {
      float acc[4] = {0.f, 0.f, 0.f, 0.f};
      const float* hp[4];
      bool val[4];
      for (int r = 0; r < 4; ++r) {
        int row = blk + (i0 + r) * NBLK;
        val[r] = (row < 12800);
        hp[r] = val[r] ? (hs + (size_t)(row % TSTEPS) * 12800 + (row / TSTEPS) * UNITSN + ks * 100)
                       : hs;
      }
      if (j < 121) {
        const float* wp = Wmdn + (ks * 100) * 121 + j;
        for (int k = 0; k < 100; ++k) {
          float wv = wp[(size_t)k * 121];
#pragma unroll
          for (int r = 0; r < 4; ++r) acc[r] = fmaf(hp[r][k], wv, acc[r]);
        }
      }
      for (int r = 0; r < 4; ++r) {
        zpart[tid] = acc[r];
        __syncthreads();
        if (tid < 121)
          zbuf[tid] = zpart[tid] + zpart[tid + 128] + zpart[tid + 256] + zpart[tid + 384] + bmdn[tid];
        __syncthreads();
        if (tid == 0) {
          float mx = zbuf[0];
          for (int q = 1; q < 20; ++q) mx = fmaxf(mx, zbuf[q]);
          float s = 0.f;
          for (int q = 0; q < 20; ++q) s += __expf(zbuf[q] - mx);
          zbuf[126] = mx;
          zbuf[127] = 1.f / s;
        }
        __syncthreads();
        if (val[r] && tid < 121) {
          int row = blk + (i0 + r) * NBLK;
          float y = zbuf[tid], o;
          if (tid < 20)       o = __expf(y - zbuf[126]) * zbuf[127];  // softmax(pi)
          else if (tid < 60)  o = y;                                   // mu1, mu2
          else if (tid < 100) o = __expf(y);                           // s1, s2
          else if (tid < 120) o = tanhf_(y);                           // rho
          else                o = sigf(y);                             // eos
          dout[(size_t)row * 121 + tid] = o;
        }
        __syncthreads();
      }
    }
  }
}

extern "C" void kernel_launch(void* const* d_in, const int* in_sizes, int n_in,
                              void* d_out, int out_size, void* d_ws, size_t ws_size,
                              hipStream_t stream) {
  const float* xs   = (const float*)d_in[0];
  const int*   chrs = (const int*)d_in[1];
  const int*   lens = (const int*)d_in[2];
  const float* Wx0  = (const float*)d_in[3];
  const float* Wh0  = (const float*)d_in[4];
  const float* b0   = (const float*)d_in[5];
  const float* p0   = (const float*)d_in[6];
  const float* Wx1  = (const float*)d_in[7];
  const float* Wh1  = (const float*)d_in[8];
  const float* b1   = (const float*)d_in[9];
  const float* p1   = (const float*)d_in[10];
  const float* Wx2  = (const float*)d_in[11];
  const float* Wh2  = (const float*)d_in[12];
  const float* b2   = (const float*)d_in[13];
  const float* p2   = (const float*)d_in[14];
  const float* Watt = (const float*)d_in[15];
  const float* batt = (const float*)d_in[16];
  const float* Wmdn = (const float*)d_in[17];
  const float* bmdn = (const float*)d_in[18];

  // zero barrier + h/w state (ws is poisoned 0xAA before every timed launch)
  hipMemsetAsync(d_ws, 0, STATE_BYTES, stream);
  hipLaunchKernelGGL(hand_kernel, dim3(NBLK), dim3(NTHR), 0, stream,
                     xs, chrs, lens, Wx0, Wh0, b0, p0, Wx1, Wh1, b1, p1,
                     Wx2, Wh2, b2, p2, Watt, batt, Wmdn, bmdn,
                     (float*)d_out, (float*)d_ws);
}